// Round 1
// baseline (526.438 us; speedup 1.0000x reference)
//
#include <hip/hip_runtime.h>

#define MARGIN 0.3f
#define NEG_INF -1e9f

typedef __attribute__((ext_vector_type(4))) float f32x4;
typedef __attribute__((ext_vector_type(8))) short short8;

// fp32 -> bf16, round-to-nearest-even (inputs are finite normals; no NaN path needed)
static __device__ __forceinline__ short f2bf(float f) {
    unsigned u = __float_as_uint(f);
    u += 0x7fffu + ((u >> 16) & 1u);
    return (short)(u >> 16);
}

// One wave (64 lanes) per sample. Block = 256 threads = 4 samples.
__global__ __launch_bounds__(256) void cf_loss_kernel(
    const float* __restrict__ emb,    // [B,16,768]
    const int*   __restrict__ labels, // [B,16]
    float* __restrict__ ws,           // ws[0]=loss_sum, ws[1]=count
    int B)
{
    const int lane = threadIdx.x & 63;
    const int w    = threadIdx.x >> 6;
    const int s    = blockIdx.x * 4 + w;
    const bool active = (s < B);
    const int sc   = active ? s : (B - 1);   // clamped for safe addressing

    const int m    = lane & 15;   // row of E this lane loads / col of C this lane holds
    const int quad = lane >> 4;

    __shared__ float sG[4][256];   // per-wave 16x16 Gram
    __shared__ float sRN[4][16];   // per-wave reciprocal norms
    __shared__ float pSum[4];
    __shared__ float pCnt[4];

    // ---- Gram via MFMA: G = E * E^T (pass same fragment as A and B) ----
    f32x4 acc = {0.f, 0.f, 0.f, 0.f};
    const float* rowp = emb + ((size_t)sc * 16 + m) * 768 + quad * 8;
    #pragma unroll 4
    for (int c = 0; c < 24; ++c) {
        f32x4 x = *(const f32x4*)(rowp);
        f32x4 y = *(const f32x4*)(rowp + 4);
        rowp += 32;
        short8 frag;
        frag[0] = f2bf(x[0]); frag[1] = f2bf(x[1]);
        frag[2] = f2bf(x[2]); frag[3] = f2bf(x[3]);
        frag[4] = f2bf(y[0]); frag[5] = f2bf(y[1]);
        frag[6] = f2bf(y[2]); frag[7] = f2bf(y[3]);
        acc = __builtin_amdgcn_mfma_f32_16x16x32_bf16(frag, frag, acc, 0, 0, 0);
    }

    // C/D layout: col = lane&15, row = quad*4 + reg  (G symmetric, so either way works)
    #pragma unroll
    for (int r = 0; r < 4; ++r)
        sG[w][(quad * 4 + r) * 16 + m] = acc[r];
    __syncthreads();

    // ---- epilogue: norms, masks, masked max, relu ----
    int lab = -1;
    if (lane < 16) lab = labels[sc * 16 + lane];
    unsigned long long posmask = __ballot(lane < 16 && lab == 1);
    unsigned long long negmask = __ballot(lane < 16 && lab == 0);
    const bool valid = (posmask != 0ull) && (negmask != 0ull);

    if (lane < 16) {
        float d = sG[w][lane * 17];                 // diagonal = ||e||^2
        sRN[w][lane] = 1.0f / fmaxf(sqrtf(d), 1e-12f);
    }
    __syncthreads();

    float contrib = 0.0f;
    if (active && valid && lane < 16 && lab == 1) {
        float rni = sRN[w][lane];
        float mx = NEG_INF;
        #pragma unroll
        for (int j = 0; j < 16; ++j) {
            bool isneg = (negmask >> j) & 1ull;
            float v = isneg ? sG[w][lane * 16 + j] * (rni * sRN[w][j]) : NEG_INF;
            mx = fmaxf(mx, v);
        }
        contrib = fmaxf(mx + MARGIN, 0.0f);
    }

    // wave reduce (nonzero only in lanes 0..15)
    contrib += __shfl_xor(contrib, 1);
    contrib += __shfl_xor(contrib, 2);
    contrib += __shfl_xor(contrib, 4);
    contrib += __shfl_xor(contrib, 8);

    if (lane == 0) {
        pSum[w] = contrib;
        pCnt[w] = (active && valid) ? (float)__popcll(posmask) : 0.0f;
    }
    __syncthreads();

    if (threadIdx.x == 0) {
        float ssum = pSum[0] + pSum[1] + pSum[2] + pSum[3];
        float scnt = pCnt[0] + pCnt[1] + pCnt[2] + pCnt[3];
        atomicAdd(&ws[0], ssum);
        atomicAdd(&ws[1], scnt);
    }
}

__global__ void cf_finalize_kernel(const float* __restrict__ ws,
                                   float* __restrict__ out)
{
    out[0] = ws[0] / fmaxf(ws[1], 1.0f);
}

extern "C" void kernel_launch(void* const* d_in, const int* in_sizes, int n_in,
                              void* d_out, int out_size, void* d_ws, size_t ws_size,
                              hipStream_t stream) {
    const float* emb    = (const float*)d_in[0];
    const int*   labels = (const int*)d_in[1];
    float* out = (float*)d_out;
    float* ws  = (float*)d_ws;

    const int B = in_sizes[0] / (16 * 768);   // 8192

    // d_ws is poisoned 0xAA before every launch — zero the accumulators.
    hipMemsetAsync(ws, 0, 2 * sizeof(float), stream);

    const int blocks = (B + 3) / 4;           // 4 samples (waves) per block
    cf_loss_kernel<<<blocks, 256, 0, stream>>>(emb, labels, ws, B);
    cf_finalize_kernel<<<1, 1, 0, stream>>>(ws, out);
}

// Round 2
// 523.185 us; speedup vs baseline: 1.0062x; 1.0062x over previous
//
#include <hip/hip_runtime.h>

#define MARGIN 0.3f
#define NEG_INF -1e9f

typedef __attribute__((ext_vector_type(4))) float f32x4;
typedef __attribute__((ext_vector_type(8))) short short8;
typedef __attribute__((ext_vector_type(4))) unsigned int u32x4;

// One wave (64 lanes) per sample; block = 256 threads = 4 samples.
// Gram G = E*E^T via mfma_f32_16x16x32_bf16 (same fragment as A and B);
// normalize post-hoc: sim[i][j] = G[i][j] / (max(sqrt(Gii),eps)*max(sqrt(Gjj),eps)).
__global__ __launch_bounds__(256, 4) void cf_loss_kernel(
    const float* __restrict__ emb,    // [B,16,768] fp32
    const int*   __restrict__ labels, // [B,16] (int32 per harness)
    float* __restrict__ ws,           // [0..255] loss-sum buckets, [256..511] count buckets
    int B)
{
    const int lane = threadIdx.x & 63;
    const int w    = threadIdx.x >> 6;
    const int s    = blockIdx.x * 4 + w;
    const bool active = (s < B);
    const int sc   = active ? s : 0;

    const int m    = lane & 15;   // row of E this lane loads (A-frag m index)
    const int quad = lane >> 4;

    __shared__ float sG[4][16 * 17];   // per-wave 16x16 Gram, stride 17 (bank-conflict pad)

    // prefetch labels early so the load overlaps the main loop
    int lab = -1;
    if (lane < 16) lab = labels[sc * 16 + lane];

    // ---- Gram via MFMA ----
    f32x4 acc = {0.f, 0.f, 0.f, 0.f};
    const float* rowp = emb + ((size_t)sc * 16 + m) * 768 + quad * 8;
    #pragma unroll 8
    for (int c = 0; c < 24; ++c) {
        f32x4 x = *(const f32x4*)(rowp);
        f32x4 y = *(const f32x4*)(rowp + 4);   // contiguous 32B per lane per iter
        rowp += 32;
        // fp32 -> bf16 by truncation: one v_perm_b32 packs two floats' high halves.
        union { short8 s8; u32x4 u4; } frag;
        frag.u4[0] = __builtin_amdgcn_perm(__float_as_uint(x[1]), __float_as_uint(x[0]), 0x07060302u);
        frag.u4[1] = __builtin_amdgcn_perm(__float_as_uint(x[3]), __float_as_uint(x[2]), 0x07060302u);
        frag.u4[2] = __builtin_amdgcn_perm(__float_as_uint(y[1]), __float_as_uint(y[0]), 0x07060302u);
        frag.u4[3] = __builtin_amdgcn_perm(__float_as_uint(y[3]), __float_as_uint(y[2]), 0x07060302u);
        acc = __builtin_amdgcn_mfma_f32_16x16x32_bf16(frag.s8, frag.s8, acc, 0, 0, 0);
    }

    // C/D layout: col = lane&15, row = quad*4 + reg (G symmetric → orientation moot)
    #pragma unroll
    for (int r = 0; r < 4; ++r)
        sG[w][(quad * 4 + r) * 17 + m] = acc[r];
    __syncthreads();   // single barrier: order G stores vs reads (cross-lane within wave)

    unsigned long long posmask = __ballot(lane < 16 && lab == 1);
    unsigned long long negmask = __ballot(lane < 16 && lab == 0);
    const bool valid = (posmask != 0ull) && (negmask != 0ull);

    // reciprocal norm from the diagonal (lanes 0..15), broadcast via shuffle below
    float rnv = 0.f;
    if (lane < 16) rnv = 1.0f / fmaxf(sqrtf(sG[w][lane * 18]), 1e-12f);

    // masked max over negatives — computed convergently, masked at the end
    float mx = NEG_INF;
    #pragma unroll
    for (int j = 0; j < 16; ++j) {
        float rj = __shfl(rnv, j);
        float v  = sG[w][m * 17 + j] * (rnv * rj);
        bool isneg = (negmask >> j) & 1ull;
        mx = fmaxf(mx, isneg ? v : NEG_INF);
    }
    float contrib = (active && valid && lane < 16 && lab == 1)
                        ? fmaxf(mx + MARGIN, 0.f) : 0.f;

    // reduce lanes 0..15 into lane 0
    contrib += __shfl_xor(contrib, 1);
    contrib += __shfl_xor(contrib, 2);
    contrib += __shfl_xor(contrib, 4);
    contrib += __shfl_xor(contrib, 8);

    if (lane == 0) {
        const int bucket = s & 255;   // 256 buckets → ~32 waves/bucket, low contention
        atomicAdd(&ws[bucket], contrib);
        float cnt = (active && valid) ? (float)__popcll(posmask) : 0.f;
        atomicAdd(&ws[256 + bucket], cnt);
    }
}

__global__ void cf_finalize_kernel(const float* __restrict__ ws,
                                   float* __restrict__ out)
{
    const int t = threadIdx.x;   // 64 threads
    float s = ws[t] + ws[t + 64] + ws[t + 128] + ws[t + 192];
    float c = ws[256 + t] + ws[256 + t + 64] + ws[256 + t + 128] + ws[256 + t + 192];
    #pragma unroll
    for (int o = 1; o < 64; o <<= 1) {
        s += __shfl_xor(s, o);
        c += __shfl_xor(c, o);
    }
    if (t == 0) out[0] = s / fmaxf(c, 1.0f);
}

extern "C" void kernel_launch(void* const* d_in, const int* in_sizes, int n_in,
                              void* d_out, int out_size, void* d_ws, size_t ws_size,
                              hipStream_t stream) {
    const float* emb    = (const float*)d_in[0];
    const int*   labels = (const int*)d_in[1];
    float* out = (float*)d_out;
    float* ws  = (float*)d_ws;

    const int B = in_sizes[0] / (16 * 768);   // 8192

    // ws is poisoned 0xAA before every launch — zero the 512 bucket floats.
    hipMemsetAsync(ws, 0, 512 * sizeof(float), stream);

    const int blocks = (B + 3) / 4;
    cf_loss_kernel<<<blocks, 256, 0, stream>>>(emb, labels, ws, B);
    cf_finalize_kernel<<<1, 64, 0, stream>>>(ws, out);
}